// Round 4
// baseline (8495.508 us; speedup 1.0000x reference)
//
#include <hip/hip_runtime.h>
#include <cstdint>
#include <cstddef>

// Problem constants
#define HN 304      // hidden size
#define G3 912      // 3*HN gate rows
#define US 76       // hidden units per slice (HN/4)
#define RS 228      // rows per slice (3*US)
#define NB 64       // batch
#define TSTEPS 1024 // encoder steps
#define LDEC 127    // decoder steps actually needed (L-1)
#define DCLS 128    // vocab / classes

// Output layout (floats): [softmax_cal 8128*128][target_cal 8128][asr_outputs 8128]
#define OUT_O1 1040384
#define OUT_O2 1048512

// Workspace layout (bytes). Proven available: ws_size >= 239,702,784.
static const size_t OFF_GI   = 0;             // 64*1024*912 f32 = 239,075,328
static const size_t OFF_HG   = 239075328ull;  // h ping-pong: 2*64*304 f32 = 155,648
static const size_t OFF_SF   = 239230976ull;  // h flags: 64*4 int = 1,024
static const size_t OFF_AM   = 239232000ull;  // argmax tagged: 64*4 ull = 2,048
static const size_t OFF_ABRT = 239234048ull;  // 256
static const size_t OFF_TAB  = 239234304ull;  // 128*912 f32 = 466,944
static const size_t WS_NEED  = 239701248ull;  // <= proven bound

// ---------------------------------------------------------------------------
// Phase 1: gi[b,t,:] = x[b,t,:] @ enc_Wih^T + enc_bih   (M=65536, N=912, K=304)
// ---------------------------------------------------------------------------
__global__ __launch_bounds__(256) void gi_gemm(const float* __restrict__ X,
                                               const float* __restrict__ W,
                                               const float* __restrict__ bias,
                                               float* __restrict__ out)
{
    __shared__ float xs[16][68];
    __shared__ float wsm[16][68];
    const int tid = threadIdx.x;
    const int m0 = blockIdx.x * 64;
    const int n0 = blockIdx.y * 64;
    const int tx = tid & 15, ty = tid >> 4;
    const int lr = tid >> 2;
    const int lk = (tid & 3) * 4;
    float c[4][4];
#pragma unroll
    for (int i = 0; i < 4; ++i)
#pragma unroll
        for (int j = 0; j < 4; ++j) c[i][j] = 0.f;

    for (int k0 = 0; k0 < HN; k0 += 16) {
        float4 xv = *(const float4*)(X + (size_t)(m0 + lr) * HN + k0 + lk);
        float4 wv = make_float4(0.f, 0.f, 0.f, 0.f);
        if (n0 + lr < G3) wv = *(const float4*)(W + (size_t)(n0 + lr) * HN + k0 + lk);
        xs[lk + 0][lr] = xv.x; xs[lk + 1][lr] = xv.y; xs[lk + 2][lr] = xv.z; xs[lk + 3][lr] = xv.w;
        wsm[lk + 0][lr] = wv.x; wsm[lk + 1][lr] = wv.y; wsm[lk + 2][lr] = wv.z; wsm[lk + 3][lr] = wv.w;
        __syncthreads();
#pragma unroll
        for (int kk = 0; kk < 16; ++kk) {
            const float4 a4 = *(const float4*)&xs[kk][ty * 4];
            const float4 b4 = *(const float4*)&wsm[kk][tx * 4];
            c[0][0] += a4.x * b4.x; c[0][1] += a4.x * b4.y; c[0][2] += a4.x * b4.z; c[0][3] += a4.x * b4.w;
            c[1][0] += a4.y * b4.x; c[1][1] += a4.y * b4.y; c[1][2] += a4.y * b4.z; c[1][3] += a4.y * b4.w;
            c[2][0] += a4.z * b4.x; c[2][1] += a4.z * b4.y; c[2][2] += a4.z * b4.z; c[2][3] += a4.z * b4.w;
            c[3][0] += a4.w * b4.x; c[3][1] += a4.w * b4.y; c[3][2] += a4.w * b4.z; c[3][3] += a4.w * b4.w;
        }
        __syncthreads();
    }
#pragma unroll
    for (int i = 0; i < 4; ++i) {
        const int m = m0 + ty * 4 + i;
#pragma unroll
        for (int j = 0; j < 4; ++j) {
            const int n = n0 + tx * 4 + j;
            if (n < G3) out[(size_t)m * G3 + n] = c[i][j] + bias[n];
        }
    }
}

// ---------------------------------------------------------------------------
// Phase 1b: decoder input-projection table
// ---------------------------------------------------------------------------
__global__ __launch_bounds__(256) void table_k(const float* __restrict__ emb,
                                               const float* __restrict__ Wih,
                                               const float* __restrict__ bih,
                                               float* __restrict__ tab)
{
    const int idx = blockIdx.x * 256 + threadIdx.x;  // 456*256 = 116736 = 128*912
    const int d = idx / G3;
    const int R = idx - d * G3;
    const float4* e4 = (const float4*)(emb + (size_t)d * HN);
    const float4* w4 = (const float4*)(Wih + (size_t)R * HN);
    float acc = 0.f;
#pragma unroll
    for (int j = 0; j < 76; ++j) {
        const float4 e = e4[j], w = w4[j];
        acc += e.x * w.x; acc += e.y * w.y; acc += e.z * w.z; acc += e.w * w.w;
    }
    tab[idx] = acc + bih[R];
}

// target_cal output
__global__ void tcal_k(const int* __restrict__ target, float* __restrict__ out)
{
    const int i = blockIdx.x * 256 + threadIdx.x;
    if (i < NB * LDEC) {
        const int b = i / LDEC;
        const int t = i - b * LDEC;
        out[OUT_O1 + i] = (float)target[b * 128 + t + 1];
    }
}

// relaxed-only spin (no acquire: agent-scope acquire emits buffer_inv — the
// R1/R2 killer). Relaxed agent atomics = sc0 sc1, served at L3, no cache ops.
__device__ __forceinline__ void spin_ge(int* f, int tgt, int* abortf)
{
    int g = 0;
    while (__hip_atomic_load(f, __ATOMIC_RELAXED, __HIP_MEMORY_SCOPE_AGENT) < tgt) {
        if ((++g & 255) == 0) {
            if (__hip_atomic_load(abortf, __ATOMIC_RELAXED, __HIP_MEMORY_SCOPE_AGENT) != 0) return;
            if (g > (1 << 19)) {  // deadlock valve: fail loudly, don't hang
                __hip_atomic_store(abortf, 1, __ATOMIC_RELAXED, __HIP_MEMORY_SCOPE_AGENT);
                return;
            }
        }
    }
    __asm__ volatile("" ::: "memory");  // compiler barrier: no load hoisting above spin
}

// tagged 8B poll: wait until tag (high 32b, signed) >= want, return payload
__device__ __forceinline__ unsigned long long spin_tag(unsigned long long* p, int want, int* abortf)
{
    int g = 0;
    unsigned long long r;
    for (;;) {
        r = __hip_atomic_load(p, __ATOMIC_RELAXED, __HIP_MEMORY_SCOPE_AGENT);
        if ((int)(r >> 32) >= want) break;
        if ((++g & 255) == 0) {
            if (__hip_atomic_load(abortf, __ATOMIC_RELAXED, __HIP_MEMORY_SCOPE_AGENT) != 0) break;
            if (g > (1 << 19)) {
                __hip_atomic_store(abortf, 1, __ATOMIC_RELAXED, __HIP_MEMORY_SCOPE_AGENT);
                break;
            }
        }
    }
    __asm__ volatile("" ::: "memory");
    return r;
}

__device__ __forceinline__ float ull_lo(unsigned long long v) { return __uint_as_float((unsigned)v); }
__device__ __forceinline__ float ull_hi(unsigned long long v) { return __uint_as_float((unsigned)(v >> 32)); }

// ---------------------------------------------------------------------------
// Phase 2: persistent recurrence. 256 WGs x 1024 threads, 1 WG/CU.
// WG w: batch b = w & 63, slice s = w >> 6.
// Encoder step t (2 barriers):
//   GEMV: ks==s group reads own h-slice from LDS; remote groups spin flags[ks]>=t
//         then load h-slice ks DIRECTLY global->reg (8B relaxed atomics, L1-bypass),
//         overlapping the L3 round-trip with own-slice FMAs.  (t==0: h=0, skip.)
//   barrier; tid<76: reduce+activation -> hbuf[u] + global h store; barrier;
//   tid0 publishes flags[s]=t+1 (h stores drained by barrier's vmcnt(0)).
// Overwrite safety (parity buffer flag&1): publishing t+1 requires this WG's
// remote groups to have consumed h_t from all partners -> h_t's buffer is only
// rewritten (at t+2) after all partners published t+1, i.e. consumed h_t.
// __launch_bounds__(1024,4): 128-VGPR cap so wreg (76 f32) stays in real VGPRs
// (R3 showed VGPR_Count=64 -> weights were AGPR-parked, doubling GEMV VALU).
// ---------------------------------------------------------------------------
__global__ __launch_bounds__(1024, 4) void rnn_persist(
    const float* __restrict__ gi,
    const float* __restrict__ encWhh, const float* __restrict__ encBhh,
    const float* __restrict__ decWhh, const float* __restrict__ decBhh,
    const float* __restrict__ tab,
    const float* __restrict__ linW, const float* __restrict__ linB,
    const int* __restrict__ target,
    float* hglob, int* syncF, unsigned long long* amax, int* abortf, float* out)
{
    const int w = blockIdx.x;
    const int b = w & 63;
    const int s = w >> 6;
    const int tid = threadIdx.x;

    __shared__ alignas(16) float hbuf[HN];
    __shared__ alignas(16) float part[4][RS];
    __shared__ alignas(16) float lpart[32][9];
    __shared__ float logit_s[32];
    __shared__ float amx_v[4];
    __shared__ int   amx_i[4];

    const int ks = tid / RS;           // k-slice 0..3 (tid>=912 idle in GEMV)
    const int lr = tid - ks * RS;      // local row 0..227
    const bool comp = (tid < 912);
    const int g = lr / US;             // gate 0=r,1=z,2=n
    const int ul = lr - g * US;        // unit within slice
    const int Rrow = g * HN + s * US + ul;
    const int u = s * US + tid;        // global hidden unit for tid<76
    const int cq = tid / US;           // slice owning unit `tid` (tid<304)

    int* flags = syncF + b * 4;
    unsigned long long* amx = amax + b * 4;

    // ---- encoder Whh slice into registers (76 f32 per thread)
    float4 wreg[19];
    if (comp) {
        const float4* wp = (const float4*)(encWhh + (size_t)Rrow * HN + (size_t)ks * US);
#pragma unroll
        for (int j = 0; j < 19; ++j) wreg[j] = wp[j];
    }
    float b_r = 0.f, b_z = 0.f, b_n = 0.f;
    if (tid < US) { b_r = encBhh[u]; b_z = encBhh[HN + u]; b_n = encBhh[2 * HN + u]; }

    for (int i = tid; i < HN; i += 1024) hbuf[i] = 0.f;   // h0 = 0
    __syncthreads();

    const float* gib = gi + (size_t)b * TSTEPS * G3;
    // 8B view of this (b, ks-slice) h vector in each parity buffer
    unsigned long long* hp8base = (unsigned long long*)hglob + ((size_t)b * HN + (size_t)ks * US) / 2;
    const size_t par8 = (size_t)NB * HN / 2;   // ull stride between parity buffers

    // ================= encoder: 1024 steps =================
    for (int t = 0; t < TSTEPS; ++t) {
        float gr = 0.f, gz = 0.f, gn = 0.f;
        if (tid < US) {                       // gi prefetch (issues before any spin)
            const float* gp = gib + (size_t)t * G3;
            gr = gp[u]; gz = gp[HN + u]; gn = gp[2 * HN + u];
        }
        if (comp) {
            float acc0 = 0.f, acc1 = 0.f;
            if (ks == s) {                    // own slice: LDS broadcast reads
                const float4* hp = (const float4*)(hbuf + s * US);
#pragma unroll
                for (int j = 0; j < 19; ++j) {
                    const float4 h4 = hp[j], w4 = wreg[j];
                    acc0 += w4.x * h4.x; acc1 += w4.y * h4.y;
                    acc0 += w4.z * h4.z; acc1 += w4.w * h4.w;
                }
            } else if (t > 0) {               // remote slice: direct global->reg
                spin_ge(&flags[ks], t, abortf);
                unsigned long long* hp8 = hp8base + (size_t)(t & 1) * par8;
#pragma unroll
                for (int j = 0; j < 19; ++j) {
                    const unsigned long long ra =
                        __hip_atomic_load(&hp8[2 * j], __ATOMIC_RELAXED, __HIP_MEMORY_SCOPE_AGENT);
                    const unsigned long long rb =
                        __hip_atomic_load(&hp8[2 * j + 1], __ATOMIC_RELAXED, __HIP_MEMORY_SCOPE_AGENT);
                    const float4 w4 = wreg[j];
                    acc0 += w4.x * ull_lo(ra); acc1 += w4.y * ull_hi(ra);
                    acc0 += w4.z * ull_lo(rb); acc1 += w4.w * ull_hi(rb);
                }
            }                                  // t==0: h0==0 -> partial stays 0
            part[ks][lr] = acc0 + acc1;
        }
        __syncthreads();                      // barrier 1
        if (tid < US) {
            const float ghr = part[0][tid] + part[1][tid] + part[2][tid] + part[3][tid] + b_r;
            const float ghz = part[0][US + tid] + part[1][US + tid] + part[2][US + tid] + part[3][US + tid] + b_z;
            const float ghn = part[0][2 * US + tid] + part[1][2 * US + tid] + part[2][2 * US + tid] + part[3][2 * US + tid] + b_n;
            const float r = 1.f / (1.f + expf(-(gr + ghr)));
            const float z = 1.f / (1.f + expf(-(gz + ghz)));
            const float n = tanhf(gn + r * ghn);
            const float hnew = (1.f - z) * n + z * hbuf[u];
            hbuf[u] = hnew;                   // own slice for next step's LDS read
            __hip_atomic_store(&hglob[((t + 1) & 1) * NB * HN + b * HN + u], hnew,
                               __ATOMIC_RELAXED, __HIP_MEMORY_SCOPE_AGENT);
        }
        __syncthreads();                      // barrier 2: h stores drained (vmcnt 0)
        if (tid == 0)
            __hip_atomic_store(&flags[s], t + 1, __ATOMIC_RELAXED, __HIP_MEMORY_SCOPE_AGENT);
    }

    // ---- bridge: fill hbuf with the full h_enc (flag 1024, parity 0)
    if (tid < HN && cq != s) {
        spin_ge(&flags[cq], TSTEPS, abortf);
        hbuf[tid] = __uint_as_float((unsigned)__hip_atomic_load(
            (unsigned int*)&hglob[0 * NB * HN + b * HN + tid],
            __ATOMIC_RELAXED, __HIP_MEMORY_SCOPE_AGENT));
    }
    // ---- decoder weights
    if (comp) {
        const float4* wp = (const float4*)(decWhh + (size_t)Rrow * HN + (size_t)ks * US);
#pragma unroll
        for (int j = 0; j < 19; ++j) wreg[j] = wp[j];
    }
    if (tid < US) { b_r = decBhh[u]; b_z = decBhh[HN + u]; b_n = decBhh[2 * HN + u]; }
    int tok = target[b * 128];         // target[b,0,0]
    const int lrow = tid >> 3;         // logit row within slice (tid<256)
    const int lks = tid & 7;           // 8 k-slices of 38
    __syncthreads();                   // hbuf complete

    // ================= decoder: 127 steps =================
    for (int t = 0; t < LDEC; ++t) {
        const int hflagv = TSTEPS + 1 + t;    // flag for the h this step produces
        const int bufn = hflagv & 1;
        float gr = 0.f, gz = 0.f, gn = 0.f;
        if (tid < US) {
            const float* tp = tab + (size_t)tok * G3;
            gr = tp[u]; gz = tp[HN + u]; gn = tp[2 * HN + u];
        }
        if (comp) {                            // full h is in hbuf (fresh)
            const float4* hp = (const float4*)(hbuf + ks * US);
            float acc0 = 0.f, acc1 = 0.f;
#pragma unroll
            for (int j = 0; j < 19; ++j) {
                const float4 h4 = hp[j], w4 = wreg[j];
                acc0 += w4.x * h4.x; acc1 += w4.y * h4.y;
                acc0 += w4.z * h4.z; acc1 += w4.w * h4.w;
            }
            part[ks][lr] = acc0 + acc1;
        }
        __syncthreads();
        if (tid < US) {
            const float ghr = part[0][tid] + part[1][tid] + part[2][tid] + part[3][tid] + b_r;
            const float ghz = part[0][US + tid] + part[1][US + tid] + part[2][US + tid] + part[3][US + tid] + b_z;
            const float ghn = part[0][2 * US + tid] + part[1][2 * US + tid] + part[2][2 * US + tid] + part[3][2 * US + tid] + b_n;
            const float r = 1.f / (1.f + expf(-(gr + ghr)));
            const float z = 1.f / (1.f + expf(-(gz + ghz)));
            const float n = tanhf(gn + r * ghn);
            const float hnew = (1.f - z) * n + z * hbuf[u];
            hbuf[u] = hnew;
            __hip_atomic_store(&hglob[bufn * NB * HN + b * HN + u], hnew,
                               __ATOMIC_RELAXED, __HIP_MEMORY_SCOPE_AGENT);
        }
        __syncthreads();                      // h stores drained
        if (tid == 0)
            __hip_atomic_store(&flags[s], hflagv, __ATOMIC_RELAXED, __HIP_MEMORY_SCOPE_AGENT);
        if (tid < HN && cq != s) {            // refill hbuf remote slices
            spin_ge(&flags[cq], hflagv, abortf);
            hbuf[tid] = __uint_as_float((unsigned)__hip_atomic_load(
                (unsigned int*)&hglob[bufn * NB * HN + b * HN + tid],
                __ATOMIC_RELAXED, __HIP_MEMORY_SCOPE_AGENT));
        }
        __syncthreads();                      // hbuf fresh for logits + next GEMV

        // logits rows [32s, 32s+32)
        if (tid < 256) {
            const float2* wl = (const float2*)(linW + (size_t)(s * 32 + lrow) * HN + (size_t)lks * 38);
            const float2* hl = (const float2*)(hbuf + lks * 38);
            float a = 0.f;
#pragma unroll
            for (int j = 0; j < 19; ++j) { const float2 wv = wl[j], hv = hl[j]; a += wv.x * hv.x; a += wv.y * hv.y; }
            lpart[lrow][lks] = a;
        }
        __syncthreads();
        if (tid < 32) {
            const float lg = lpart[tid][0] + lpart[tid][1] + lpart[tid][2] + lpart[tid][3]
                           + lpart[tid][4] + lpart[tid][5] + lpart[tid][6] + lpart[tid][7]
                           + linB[s * 32 + tid];
            logit_s[tid] = lg;
            out[((size_t)b * LDEC + t) * DCLS + s * 32 + tid] = lg;   // softmax_cal
        }
        __syncthreads();
        if (tid == 0) {                       // publish local argmax: one tagged 8B store
            float bv = logit_s[0]; int bi = 0;
            for (int i = 1; i < 32; ++i) { const float v = logit_s[i]; if (v > bv) { bv = v; bi = i; } }
            const unsigned tagf = (unsigned)(((t + 1) << 8) | (s * 32 + bi));
            const unsigned long long pk = ((unsigned long long)tagf << 32) | (unsigned long long)__float_as_uint(bv);
            __hip_atomic_store(&amx[s], pk, __ATOMIC_RELAXED, __HIP_MEMORY_SCOPE_AGENT);
        }
        if (tid < 4) {                        // poll all 4 slices' argmaxes in parallel
            const unsigned long long r = spin_tag(&amx[tid], (t + 1) << 8, abortf);
            amx_v[tid] = ull_lo(r);
            amx_i[tid] = (int)(r >> 32) & 255;
        }
        __syncthreads();
        {                                     // identical winner on all threads
            float gbv = amx_v[0]; int gbi = amx_i[0];
            if (amx_v[1] > gbv) { gbv = amx_v[1]; gbi = amx_i[1]; }
            if (amx_v[2] > gbv) { gbv = amx_v[2]; gbi = amx_i[2]; }
            if (amx_v[3] > gbv) { gbv = amx_v[3]; gbi = amx_i[3]; }
            tok = gbi;
            if (tid == 0 && s == 0) out[OUT_O2 + (size_t)b * LDEC + t] = (float)gbi;  // asr_outputs
        }
    }
}

// ---------------------------------------------------------------------------
extern "C" void kernel_launch(void* const* d_in, const int* in_sizes, int n_in,
                              void* d_out, int out_size, void* d_ws, size_t ws_size,
                              hipStream_t stream)
{
    (void)in_sizes; (void)n_in; (void)out_size;
    const float* x      = (const float*)d_in[0];
    const int*   target = (const int*)  d_in[1];
    const float* emb    = (const float*)d_in[2];
    const float* encWih = (const float*)d_in[3];
    const float* encWhh = (const float*)d_in[4];
    const float* encBih = (const float*)d_in[5];
    const float* encBhh = (const float*)d_in[6];
    const float* decWih = (const float*)d_in[7];
    const float* decWhh = (const float*)d_in[8];
    const float* decBih = (const float*)d_in[9];
    const float* decBhh = (const float*)d_in[10];
    const float* linW   = (const float*)d_in[11];
    const float* linB   = (const float*)d_in[12];
    float* out = (float*)d_out;
    char* ws = (char*)d_ws;

    if (ws_size < WS_NEED) return;  // insufficient scratch: fail visibly

    float*              gi    = (float*)(ws + OFF_GI);
    float*              hglob = (float*)(ws + OFF_HG);
    int*                syncF = (int*)  (ws + OFF_SF);
    unsigned long long* amax  = (unsigned long long*)(ws + OFF_AM);
    int*                abrt  = (int*)  (ws + OFF_ABRT);
    float*              tab   = (float*)(ws + OFF_TAB);

    // Only the abort flag must be zero. h-flags / amax tags rely on 0xAA poison
    // reading as negative (spin predicates are signed >=).
    hipMemsetAsync(ws + OFF_ABRT, 0, 256, stream);
    gi_gemm<<<dim3(1024, 15), 256, 0, stream>>>(x, encWih, encBih, gi);
    table_k<<<456, 256, 0, stream>>>(emb, decWih, decBih, tab);
    tcal_k<<<32, 256, 0, stream>>>(target, out);
    rnn_persist<<<256, 1024, 0, stream>>>(gi, encWhh, encBhh, decWhh, decBhh, tab,
                                          linW, linB, target, hglob, syncF, amax,
                                          abrt, out);
}

// Round 5
// 3331.084 us; speedup vs baseline: 2.5504x; 2.5504x over previous
//
#include <hip/hip_runtime.h>
#include <cstdint>
#include <cstddef>

// Problem constants
#define HN 304      // hidden size
#define G3 912      // 3*HN gate rows
#define US 76       // hidden units per slice (HN/4)
#define RS 228      // rows per slice (3*US)
#define NB 64       // batch
#define TSTEPS 1024 // encoder steps
#define LDEC 127    // decoder steps actually needed (L-1)
#define DCLS 128    // vocab / classes

// Output layout (floats): [softmax_cal 8128*128][target_cal 8128][asr_outputs 8128]
#define OUT_O1 1040384
#define OUT_O2 1048512

// Workspace layout (bytes). Proven available: ws_size >= 239,702,784 (R1-R4 ran).
static const size_t OFF_GI   = 0;             // 64*1024*912 f32 = 239,075,328
static const size_t OFF_HP   = 239075328ull;  // tagged h ping-pong: 2*64*304 u32 = 155,648
static const size_t OFF_AM   = 239230976ull;  // argmax tagged: 64*4 ull = 2,048
static const size_t OFF_ABRT = 239233024ull;  // 256
static const size_t OFF_TAB  = 239233280ull;  // 128*912 f32 = 466,944
static const size_t WS_NEED  = 239700224ull;  // <= proven bound

// ---------------------------------------------------------------------------
// Phase 1: gi[b,t,:] = x[b,t,:] @ enc_Wih^T + enc_bih   (M=65536, N=912, K=304)
// ---------------------------------------------------------------------------
__global__ __launch_bounds__(256) void gi_gemm(const float* __restrict__ X,
                                               const float* __restrict__ W,
                                               const float* __restrict__ bias,
                                               float* __restrict__ out)
{
    __shared__ float xs[16][68];
    __shared__ float wsm[16][68];
    const int tid = threadIdx.x;
    const int m0 = blockIdx.x * 64;
    const int n0 = blockIdx.y * 64;
    const int tx = tid & 15, ty = tid >> 4;
    const int lr = tid >> 2;
    const int lk = (tid & 3) * 4;
    float c[4][4];
#pragma unroll
    for (int i = 0; i < 4; ++i)
#pragma unroll
        for (int j = 0; j < 4; ++j) c[i][j] = 0.f;

    for (int k0 = 0; k0 < HN; k0 += 16) {
        float4 xv = *(const float4*)(X + (size_t)(m0 + lr) * HN + k0 + lk);
        float4 wv = make_float4(0.f, 0.f, 0.f, 0.f);
        if (n0 + lr < G3) wv = *(const float4*)(W + (size_t)(n0 + lr) * HN + k0 + lk);
        xs[lk + 0][lr] = xv.x; xs[lk + 1][lr] = xv.y; xs[lk + 2][lr] = xv.z; xs[lk + 3][lr] = xv.w;
        wsm[lk + 0][lr] = wv.x; wsm[lk + 1][lr] = wv.y; wsm[lk + 2][lr] = wv.z; wsm[lk + 3][lr] = wv.w;
        __syncthreads();
#pragma unroll
        for (int kk = 0; kk < 16; ++kk) {
            const float4 a4 = *(const float4*)&xs[kk][ty * 4];
            const float4 b4 = *(const float4*)&wsm[kk][tx * 4];
            c[0][0] += a4.x * b4.x; c[0][1] += a4.x * b4.y; c[0][2] += a4.x * b4.z; c[0][3] += a4.x * b4.w;
            c[1][0] += a4.y * b4.x; c[1][1] += a4.y * b4.y; c[1][2] += a4.y * b4.z; c[1][3] += a4.y * b4.w;
            c[2][0] += a4.z * b4.x; c[2][1] += a4.z * b4.y; c[2][2] += a4.z * b4.z; c[2][3] += a4.z * b4.w;
            c[3][0] += a4.w * b4.x; c[3][1] += a4.w * b4.y; c[3][2] += a4.w * b4.z; c[3][3] += a4.w * b4.w;
        }
        __syncthreads();
    }
#pragma unroll
    for (int i = 0; i < 4; ++i) {
        const int m = m0 + ty * 4 + i;
#pragma unroll
        for (int j = 0; j < 4; ++j) {
            const int n = n0 + tx * 4 + j;
            if (n < G3) out[(size_t)m * G3 + n] = c[i][j] + bias[n];
        }
    }
}

// ---------------------------------------------------------------------------
// Phase 1b: decoder input-projection table
// ---------------------------------------------------------------------------
__global__ __launch_bounds__(256) void table_k(const float* __restrict__ emb,
                                               const float* __restrict__ Wih,
                                               const float* __restrict__ bih,
                                               float* __restrict__ tab)
{
    const int idx = blockIdx.x * 256 + threadIdx.x;  // 456*256 = 116736 = 128*912
    const int d = idx / G3;
    const int R = idx - d * G3;
    const float4* e4 = (const float4*)(emb + (size_t)d * HN);
    const float4* w4 = (const float4*)(Wih + (size_t)R * HN);
    float acc = 0.f;
#pragma unroll
    for (int j = 0; j < 76; ++j) {
        const float4 e = e4[j], w = w4[j];
        acc += e.x * w.x; acc += e.y * w.y; acc += e.z * w.z; acc += e.w * w.w;
    }
    tab[idx] = acc + bih[R];
}

// target_cal output
__global__ void tcal_k(const int* __restrict__ target, float* __restrict__ out)
{
    const int i = blockIdx.x * 256 + threadIdx.x;
    if (i < NB * LDEC) {
        const int b = i / LDEC;
        const int t = i - b * LDEC;
        out[OUT_O1 + i] = (float)target[b * 128 + t + 1];
    }
}

// Poll a self-tagged h element: wait until low-2 mantissa bits == want.
// Relaxed-only (no acquire -> no buffer_inv; data IS the flag, no fence needed).
__device__ __forceinline__ unsigned poll_tag32(unsigned int* p, unsigned want, int* abortf)
{
    unsigned v; int g = 0;
    for (;;) {
        v = __hip_atomic_load(p, __ATOMIC_RELAXED, __HIP_MEMORY_SCOPE_AGENT);
        if ((v & 3u) == want) break;
        if ((++g & 255) == 0) {
            if (__hip_atomic_load(abortf, __ATOMIC_RELAXED, __HIP_MEMORY_SCOPE_AGENT) != 0) break;
            if (g > (1 << 19)) {  // deadlock valve: fail loudly, don't hang
                __hip_atomic_store(abortf, 1, __ATOMIC_RELAXED, __HIP_MEMORY_SCOPE_AGENT);
                break;
            }
        }
    }
    __asm__ volatile("" ::: "memory");
    return v;
}

// tagged 8B poll for argmax: wait until tag (high 32b, signed) >= want
__device__ __forceinline__ unsigned long long spin_tag(unsigned long long* p, int want, int* abortf)
{
    int g = 0;
    unsigned long long r;
    for (;;) {
        r = __hip_atomic_load(p, __ATOMIC_RELAXED, __HIP_MEMORY_SCOPE_AGENT);
        if ((int)(r >> 32) >= want) break;
        if ((++g & 255) == 0) {
            if (__hip_atomic_load(abortf, __ATOMIC_RELAXED, __HIP_MEMORY_SCOPE_AGENT) != 0) break;
            if (g > (1 << 19)) {
                __hip_atomic_store(abortf, 1, __ATOMIC_RELAXED, __HIP_MEMORY_SCOPE_AGENT);
                break;
            }
        }
    }
    __asm__ volatile("" ::: "memory");
    return r;
}

// ---------------------------------------------------------------------------
// Phase 2: persistent recurrence. 256 WGs x 1024 threads, 1 WG/CU.
// WG w: batch b = w & 63, slice s = w >> 6.
// h exchange: SELF-TAGGED elements. Step producing h_T stores each element as
// (float_bits & ~3) | (T & 3) into hpk[T&1][b][e] (4B relaxed agent atomic,
// sc0 sc1 -> served at L3, no cache maintenance). Consumers poll their element
// until tag == T&3: data and flag are the same word, so there is no separate
// drain/flag/fence on the critical path. Producer uses the identically tagged
// value in its own hbuf, so all 4 WGs see bit-identical h (tag costs 2^-21
// relative perturbation — negligible).
// Overwrite safety (parity slot T&1, tags mod 4): slot is rewritten at T+2;
// publishing T+2 requires having consumed partners' T+1, which partners only
// publish after consuming our T — same induction as R3. Consecutive same-slot
// tags differ by 2 mod 4, zero-init disambiguates the first two steps.
// ---------------------------------------------------------------------------
__global__ __launch_bounds__(1024) void rnn_persist(
    const float* __restrict__ gi,
    const float* __restrict__ encWhh, const float* __restrict__ encBhh,
    const float* __restrict__ decWhh, const float* __restrict__ decBhh,
    const float* __restrict__ tab,
    const float* __restrict__ linW, const float* __restrict__ linB,
    const int* __restrict__ target,
    unsigned int* hpk, unsigned long long* amax, int* abortf, float* out)
{
    const int w = blockIdx.x;
    const int b = w & 63;
    const int s = w >> 6;
    const int tid = threadIdx.x;

    __shared__ alignas(16) float hbuf[HN];
    __shared__ alignas(16) float part[4][RS];
    __shared__ alignas(16) float lpart[32][9];
    __shared__ float logit_s[32];
    __shared__ float amx_v[4];
    __shared__ int   amx_i[4];

    const int ks = tid / RS;           // k-slice 0..3 (tid>=912 idle in GEMV)
    const int lr = tid - ks * RS;      // local row 0..227
    const bool comp = (tid < 912);
    const int g = lr / US;             // gate 0=r,1=z,2=n
    const int ul = lr - g * US;        // unit within slice
    const int Rrow = g * HN + s * US + ul;
    const int u = s * US + tid;        // global hidden unit for tid<76
    const int cq = tid / US;           // slice owning element `tid` (tid<304)

    unsigned long long* amx = amax + b * 4;
    unsigned int* hpb = hpk + b * HN;  // parity stride = NB*HN

    // ---- encoder Whh slice into registers (76 f32 per thread)
    float4 wreg[19];
    if (comp) {
        const float4* wp = (const float4*)(encWhh + (size_t)Rrow * HN + (size_t)ks * US);
#pragma unroll
        for (int j = 0; j < 19; ++j) wreg[j] = wp[j];
    }
    float b_r = 0.f, b_z = 0.f, b_n = 0.f;
    if (tid < US) { b_r = encBhh[u]; b_z = encBhh[HN + u]; b_n = encBhh[2 * HN + u]; }

    for (int i = tid; i < HN; i += 1024) hbuf[i] = 0.f;   // h0 = 0
    __syncthreads();

    const float* gib = gi + (size_t)b * TSTEPS * G3;

    // ================= encoder: 1024 steps =================
    for (int t = 0; t < TSTEPS; ++t) {
        const int T = t + 1;                  // tag of the h this step produces
        float gr = 0.f, gz = 0.f, gn = 0.f;
        if (tid < US) {                       // gi prefetch, hidden behind GEMV
            const float* gp = gib + (size_t)t * G3;
            gr = gp[u]; gz = gp[HN + u]; gn = gp[2 * HN + u];
        }
        if (comp) {                           // GEMV over h_t in hbuf (LDS broadcast)
            const float4* hp = (const float4*)(hbuf + ks * US);
            float acc = 0.f;
#pragma unroll
            for (int j = 0; j < 19; ++j) {
                const float4 h4 = hp[j], w4 = wreg[j];
                acc += w4.x * h4.x; acc += w4.y * h4.y; acc += w4.z * h4.z; acc += w4.w * h4.w;
            }
            part[ks][lr] = acc;
        }
        __syncthreads();                      // barrier 1: part done, hbuf reads done
        if (tid < US) {
            const float ghr = part[0][tid] + part[1][tid] + part[2][tid] + part[3][tid] + b_r;
            const float ghz = part[0][US + tid] + part[1][US + tid] + part[2][US + tid] + part[3][US + tid] + b_z;
            const float ghn = part[0][2 * US + tid] + part[1][2 * US + tid] + part[2][2 * US + tid] + part[3][2 * US + tid] + b_n;
            const float r = 1.f / (1.f + expf(-(gr + ghr)));
            const float z = 1.f / (1.f + expf(-(gz + ghz)));
            const float n = tanhf(gn + r * ghn);
            const float hnew = (1.f - z) * n + z * hbuf[u];
            const unsigned hb = (__float_as_uint(hnew) & ~3u) | ((unsigned)T & 3u);
            hbuf[u] = __uint_as_float(hb);    // own slice, tagged (bit-identical everywhere)
            __hip_atomic_store(&hpb[(T & 1) * NB * HN + u], hb,
                               __ATOMIC_RELAXED, __HIP_MEMORY_SCOPE_AGENT);
        }
        if (tid < HN && cq != s) {            // fetch remote slices: data IS the flag
            const unsigned v = poll_tag32(&hpb[(T & 1) * NB * HN + tid],
                                          (unsigned)T & 3u, abortf);
            hbuf[tid] = __uint_as_float(v);
        }
        __syncthreads();                      // barrier 2: hbuf = h_{t+1}
    }

    // ---- decoder weights + biases
    if (comp) {
        const float4* wp = (const float4*)(decWhh + (size_t)Rrow * HN + (size_t)ks * US);
#pragma unroll
        for (int j = 0; j < 19; ++j) wreg[j] = wp[j];
    }
    if (tid < US) { b_r = decBhh[u]; b_z = decBhh[HN + u]; b_n = decBhh[2 * HN + u]; }
    int tok = target[b * 128];         // target[b,0,0]
    const int lrow = tid >> 3;         // logit row within slice (tid<256)
    const int lks = tid & 7;           // 8 k-slices of 38
    __syncthreads();

    // ================= decoder: 127 steps =================
    for (int t = 0; t < LDEC; ++t) {
        const int T = TSTEPS + 1 + t;         // h tag this step produces
        float gr = 0.f, gz = 0.f, gn = 0.f;
        if (tid < US) {
            const float* tp = tab + (size_t)tok * G3;
            gr = tp[u]; gz = tp[HN + u]; gn = tp[2 * HN + u];
        }
        if (comp) {
            const float4* hp = (const float4*)(hbuf + ks * US);
            float acc = 0.f;
#pragma unroll
            for (int j = 0; j < 19; ++j) {
                const float4 h4 = hp[j], w4 = wreg[j];
                acc += w4.x * h4.x; acc += w4.y * h4.y; acc += w4.z * h4.z; acc += w4.w * h4.w;
            }
            part[ks][lr] = acc;
        }
        __syncthreads();
        if (tid < US) {
            const float ghr = part[0][tid] + part[1][tid] + part[2][tid] + part[3][tid] + b_r;
            const float ghz = part[0][US + tid] + part[1][US + tid] + part[2][US + tid] + part[3][US + tid] + b_z;
            const float ghn = part[0][2 * US + tid] + part[1][2 * US + tid] + part[2][2 * US + tid] + part[3][2 * US + tid] + b_n;
            const float r = 1.f / (1.f + expf(-(gr + ghr)));
            const float z = 1.f / (1.f + expf(-(gz + ghz)));
            const float n = tanhf(gn + r * ghn);
            const float hnew = (1.f - z) * n + z * hbuf[u];
            const unsigned hb = (__float_as_uint(hnew) & ~3u) | ((unsigned)T & 3u);
            hbuf[u] = __uint_as_float(hb);
            __hip_atomic_store(&hpb[(T & 1) * NB * HN + u], hb,
                               __ATOMIC_RELAXED, __HIP_MEMORY_SCOPE_AGENT);
        }
        if (tid < HN && cq != s) {
            const unsigned v = poll_tag32(&hpb[(T & 1) * NB * HN + tid],
                                          (unsigned)T & 3u, abortf);
            hbuf[tid] = __uint_as_float(v);
        }
        __syncthreads();                      // hbuf = fresh h for logits

        // logits rows [32s, 32s+32)
        if (tid < 256) {
            const float2* wl = (const float2*)(linW + (size_t)(s * 32 + lrow) * HN + (size_t)lks * 38);
            const float2* hl = (const float2*)(hbuf + lks * 38);
            float a = 0.f;
#pragma unroll
            for (int j = 0; j < 19; ++j) { const float2 wv = wl[j], hv = hl[j]; a += wv.x * hv.x; a += wv.y * hv.y; }
            lpart[lrow][lks] = a;
        }
        __syncthreads();
        if (tid < 32) {
            const float lg = lpart[tid][0] + lpart[tid][1] + lpart[tid][2] + lpart[tid][3]
                           + lpart[tid][4] + lpart[tid][5] + lpart[tid][6] + lpart[tid][7]
                           + linB[s * 32 + tid];
            logit_s[tid] = lg;
            out[((size_t)b * LDEC + t) * DCLS + s * 32 + tid] = lg;   // softmax_cal
        }
        __syncthreads();
        if (tid == 0) {                       // publish local argmax: one tagged 8B store
            float bv = logit_s[0]; int bi = 0;
            for (int i = 1; i < 32; ++i) { const float v = logit_s[i]; if (v > bv) { bv = v; bi = i; } }
            const unsigned tagf = (unsigned)(((t + 1) << 8) | (s * 32 + bi));
            const unsigned long long pk = ((unsigned long long)tagf << 32) | (unsigned long long)__float_as_uint(bv);
            __hip_atomic_store(&amx[s], pk, __ATOMIC_RELAXED, __HIP_MEMORY_SCOPE_AGENT);
        }
        if (tid < 4) {                        // poll all 4 slices' argmaxes in parallel
            const unsigned long long r = spin_tag(&amx[tid], (t + 1) << 8, abortf);
            amx_v[tid] = __uint_as_float((unsigned)r);
            amx_i[tid] = (int)(r >> 32) & 255;
        }
        __syncthreads();
        {                                     // identical winner on all threads
            float gbv = amx_v[0]; int gbi = amx_i[0];
            if (amx_v[1] > gbv) { gbv = amx_v[1]; gbi = amx_i[1]; }
            if (amx_v[2] > gbv) { gbv = amx_v[2]; gbi = amx_i[2]; }
            if (amx_v[3] > gbv) { gbv = amx_v[3]; gbi = amx_i[3]; }
            tok = gbi;
            if (tid == 0 && s == 0) out[OUT_O2 + (size_t)b * LDEC + t] = (float)gbi;  // asr_outputs
        }
    }
}

// ---------------------------------------------------------------------------
extern "C" void kernel_launch(void* const* d_in, const int* in_sizes, int n_in,
                              void* d_out, int out_size, void* d_ws, size_t ws_size,
                              hipStream_t stream)
{
    (void)in_sizes; (void)n_in; (void)out_size;
    const float* x      = (const float*)d_in[0];
    const int*   target = (const int*)  d_in[1];
    const float* emb    = (const float*)d_in[2];
    const float* encWih = (const float*)d_in[3];
    const float* encWhh = (const float*)d_in[4];
    const float* encBih = (const float*)d_in[5];
    const float* encBhh = (const float*)d_in[6];
    const float* decWih = (const float*)d_in[7];
    const float* decWhh = (const float*)d_in[8];
    const float* decBih = (const float*)d_in[9];
    const float* decBhh = (const float*)d_in[10];
    const float* linW   = (const float*)d_in[11];
    const float* linB   = (const float*)d_in[12];
    float* out = (float*)d_out;
    char* ws = (char*)d_ws;

    if (ws_size < WS_NEED) return;  // insufficient scratch: fail visibly

    float*              gi   = (float*)(ws + OFF_GI);
    unsigned int*       hpk  = (unsigned int*)(ws + OFF_HP);
    unsigned long long* amax = (unsigned long long*)(ws + OFF_AM);
    int*                abrt = (int*)(ws + OFF_ABRT);
    float*              tab  = (float*)(ws + OFF_TAB);

    // zero tagged-h ping-pong (tag 0 = "unwritten"), argmax slots, abort flag
    hipMemsetAsync(ws + OFF_HP, 0, OFF_TAB - OFF_HP, stream);
    gi_gemm<<<dim3(1024, 15), 256, 0, stream>>>(x, encWih, encBih, gi);
    table_k<<<456, 256, 0, stream>>>(emb, decWih, decBih, tab);
    tcal_k<<<32, 256, 0, stream>>>(target, out);
    rnn_persist<<<256, 1024, 0, stream>>>(gi, encWhh, encBhh, decWhh, decBhh, tab,
                                          linW, linB, target, hpk, amax, abrt, out);
}